// Round 2
// baseline (183.046 us; speedup 1.0000x reference)
//
#include <hip/hip_runtime.h>

// QuantLinearW4A4Tl: M=8192, K=4096, N=4096, R=32
#define M_ 8192
#define K_ 4096
#define N_ 4096
#define R_ 32
#define KP_ (K_ / 2)

// GEMM geometry: 256x256 tile, BK=64 i8, 8 waves (2Mx4N), 4-deep LDS pipeline
#define BM 256
#define BN 256
#define BK 64
#define NT (K_ / BK)          // 64 K-tiles
#define NBUF 4
#define ABUF_SZ 16384         // 256 rows x 64 B
#define TILE_SZ 32768         // A + B
#define GRID ((M_ / BM) * (N_ / BN))   // 32 x 16 = 512

typedef __attribute__((ext_vector_type(4))) int    i32x4;
typedef __attribute__((ext_vector_type(4))) float  f32x4;
typedef __attribute__((ext_vector_type(8))) __bf16 bf16x8;

__device__ __forceinline__ void gload16(const void* g, void* l) {
  __builtin_amdgcn_global_load_lds(
      (const __attribute__((address_space(1))) unsigned int*)g,
      (__attribute__((address_space(3))) unsigned int*)l, 16, 0, 0);
}

// ---- repack: int32 (2 nibbles, 0..255) -> 2 sign-extended int8 ----
__device__ __forceinline__ unsigned nib2(int b) {
  unsigned lo = (unsigned)(((b & 15) ^ 8) - 8) & 0xFFu;
  unsigned hi = (unsigned)((((b >> 4) & 15) ^ 8) - 8) & 0xFFu;
  return lo | (hi << 8);
}

__global__ void repack_int4(const int* __restrict__ in, unsigned* __restrict__ out, int n4) {
  int stride = gridDim.x * blockDim.x;
  for (int i = blockIdx.x * blockDim.x + threadIdx.x; i < n4; i += stride) {
    int4 v = ((const int4*)in)[i];
    uint2 o;
    o.x = nib2(v.x) | (nib2(v.y) << 16);
    o.y = nib2(v.z) | (nib2(v.w) << 16);
    ((uint2*)out)[i] = o;
  }
}

// ---- f32 -> bf16 (RNE) ----
__device__ __forceinline__ unsigned short f2b(float x) {
  unsigned u = __float_as_uint(x);
  return (unsigned short)((u + 0x7FFFu + ((u >> 16) & 1u)) >> 16);
}

__global__ void f2bf4(const float* __restrict__ in, unsigned short* __restrict__ out, int n4) {
  int stride = gridDim.x * blockDim.x;
  for (int i = blockIdx.x * blockDim.x + threadIdx.x; i < n4; i += stride) {
    float4 f = ((const float4*)in)[i];
    ushort4 o;
    o.x = f2b(f.x); o.y = f2b(f.y); o.z = f2b(f.z); o.w = f2b(f.w);
    ((ushort4*)out)[i] = o;
  }
}

// ---- main GEMM: 256x256, 8 waves, 4-deep counted-vmcnt pipeline ----
// LDS per tile buffer: A-tile = 16 frags x 1 KiB (frag-major, lane-ordered:
// frag u, lane l <-> row u*16+(l&15), k-bytes (l>>4)*16); B-tile same.
// ds_read of a fragment = contiguous 16B/lane -> conflict-free; matches
// global_load_lds's linear base+lane*16 destination exactly.
__global__ __launch_bounds__(512, 2) void gemm_w4a4(
    const signed char* __restrict__ x8, const signed char* __restrict__ w8,
    const unsigned short* __restrict__ xrb, const unsigned short* __restrict__ wob,
    const float* __restrict__ xscale, const float* __restrict__ wscale,
    const float* __restrict__ bias, float* __restrict__ out)
{
  extern __shared__ __align__(16) char lds[];   // 128 KiB = 4 x 32 KiB

  const int t    = threadIdx.x;
  const int w    = t >> 6;          // wave 0..7
  const int l    = t & 63;
  const int lrow = l & 15;
  const int lgrp = l >> 4;
  const int wr   = w >> 2;          // 0..1 -> 128 output rows
  const int wc   = w & 3;           // 0..3 -> 64 output cols

  // XCD-aware bijective swizzle (512 blocks % 8 XCDs == 0)
  const int swz  = (blockIdx.x & 7) * (GRID / 8) + (blockIdx.x >> 3);
  const int m0   = (swz & 31) * BM;
  const int n0   = (swz >> 5) * BN;

  // per-lane global staging sources (frag u = j*8 + w), advance by BK per tile
  const signed char* aS0 = x8 + (size_t)(m0 + w * 16 + lrow) * K_ + lgrp * 16;
  const signed char* aS1 = x8 + (size_t)(m0 + (8 + w) * 16 + lrow) * K_ + lgrp * 16;
  const signed char* bS0 = w8 + (size_t)(n0 + w * 16 + lrow) * K_ + lgrp * 16;
  const signed char* bS1 = w8 + (size_t)(n0 + (8 + w) * 16 + lrow) * K_ + lgrp * 16;

#define STAGE_A(tile)                                                        \
  { char* d = lds + ((tile) & 3) * TILE_SZ + w * 1024;                       \
    gload16(aS0 + (size_t)(tile) * BK, d);                                   \
    gload16(aS1 + (size_t)(tile) * BK, d + 8192); }
#define STAGE_B(tile)                                                        \
  { char* d = lds + ((tile) & 3) * TILE_SZ + ABUF_SZ + w * 1024;             \
    gload16(bS0 + (size_t)(tile) * BK, d);                                   \
    gload16(bS1 + (size_t)(tile) * BK, d + 8192); }
#define FENCE asm volatile("" ::: "memory")

  i32x4 acc[8][4] = {};

  // prologue: stage tiles 0..2 (12 vmem/wave in flight), wait tile 0 (vmcnt 8)
  STAGE_A(0) STAGE_B(0)
  STAGE_A(1) STAGE_B(1)
  STAGE_A(2) STAGE_B(2)
  asm volatile("s_waitcnt vmcnt(8)" ::: "memory");
  __builtin_amdgcn_s_barrier();
  FENCE;

  for (int kt = 0; kt < NT; ++kt) {
    const char* Ab = lds + (kt & 3) * TILE_SZ;
    const char* Bb = Ab + ABUF_SZ;

    // ---- phase 1: B frags + A m-half 0; stage A of tile kt+3 ----
    i32x4 bf[4], af0[4];
    #pragma unroll
    for (int n = 0; n < 4; ++n)
      bf[n] = *(const i32x4*)(Bb + (wc * 4 + n) * 1024 + l * 16);
    #pragma unroll
    for (int m = 0; m < 4; ++m)
      af0[m] = *(const i32x4*)(Ab + (wr * 8 + m) * 1024 + l * 16);
    if (kt < NT - 3) STAGE_A(kt + 3)
    FENCE;
    __builtin_amdgcn_s_barrier();
    FENCE;
    __builtin_amdgcn_s_setprio(1);
    #pragma unroll
    for (int m = 0; m < 4; ++m)
      #pragma unroll
      for (int n = 0; n < 4; ++n)
        acc[m][n] = __builtin_amdgcn_mfma_i32_16x16x64_i8(af0[m], bf[n], acc[m][n], 0, 0, 0);
    __builtin_amdgcn_s_setprio(0);
    FENCE;
    __builtin_amdgcn_s_barrier();
    FENCE;

    // ---- phase 2: A m-half 1; stage B of tile kt+3; counted vmcnt ----
    i32x4 af1[4];
    #pragma unroll
    for (int m = 0; m < 4; ++m)
      af1[m] = *(const i32x4*)(Ab + (wr * 8 + 4 + m) * 1024 + l * 16);
    if (kt < NT - 3) {
      STAGE_B(kt + 3)
      asm volatile("s_waitcnt vmcnt(8)" ::: "memory");   // tile kt+1 landed
    } else if (kt == NT - 3) {
      asm volatile("s_waitcnt vmcnt(4)" ::: "memory");
    } else if (kt == NT - 2) {
      asm volatile("s_waitcnt vmcnt(0)" ::: "memory");
    }
    FENCE;
    __builtin_amdgcn_s_barrier();
    FENCE;
    __builtin_amdgcn_s_setprio(1);
    #pragma unroll
    for (int m = 0; m < 4; ++m)
      #pragma unroll
      for (int n = 0; n < 4; ++n)
        acc[4 + m][n] = __builtin_amdgcn_mfma_i32_16x16x64_i8(af1[m], bf[n], acc[4 + m][n], 0, 0, 0);
    __builtin_amdgcn_s_setprio(0);
    FENCE;
    __builtin_amdgcn_s_barrier();
    FENCE;
  }

  // ---- epilogue: dequant + bias + rank-32 outlier via bf16 MFMA ----
  f32x4 sxv[8];
  #pragma unroll
  for (int m = 0; m < 8; ++m)
    sxv[m] = *(const f32x4*)(xscale + m0 + wr * 128 + m * 16 + lgrp * 4);
  float swv[4], bv[4];
  #pragma unroll
  for (int n = 0; n < 4; ++n) {
    int cg = n0 + wc * 64 + n * 16 + lrow;
    swv[n] = wscale[cg];
    bv[n]  = bias[cg];
  }
  bf16x8 ar[8], br[4];
  #pragma unroll
  for (int m = 0; m < 8; ++m)
    ar[m] = *(const bf16x8*)(xrb + (size_t)(m0 + wr * 128 + m * 16 + lrow) * R_ + lgrp * 8);
  #pragma unroll
  for (int n = 0; n < 4; ++n)
    br[n] = *(const bf16x8*)(wob + (size_t)(n0 + wc * 64 + n * 16 + lrow) * R_ + lgrp * 8);

  #pragma unroll
  for (int m = 0; m < 8; ++m) {
    #pragma unroll
    for (int n = 0; n < 4; ++n) {
      f32x4 z = {0.0f, 0.0f, 0.0f, 0.0f};
      f32x4 c = __builtin_amdgcn_mfma_f32_16x16x32_bf16(ar[m], br[n], z, 0, 0, 0);
      #pragma unroll
      for (int j = 0; j < 4; ++j) {
        int rg = m0 + wr * 128 + m * 16 + lgrp * 4 + j;   // C/D: row=(l>>4)*4+j
        int cg = n0 + wc * 64 + n * 16 + lrow;            //      col=l&15
        out[(size_t)rg * N_ + cg] =
            (float)acc[m][n][j] * sxv[m][j] * swv[n] + c[j] + bv[n];
      }
    }
  }
}

extern "C" void kernel_launch(void* const* d_in, const int* in_sizes, int n_in,
                              void* d_out, int out_size, void* d_ws, size_t ws_size,
                              hipStream_t stream) {
  const int*   x_quant   = (const int*)d_in[0];
  const float* x_scale   = (const float*)d_in[1];
  const int*   weight    = (const int*)d_in[2];
  const float* w_scales  = (const float*)d_in[3];
  const float* bias      = (const float*)d_in[4];
  const float* x_r       = (const float*)d_in[5];
  const float* w_outlier = (const float*)d_in[6];
  float* out = (float*)d_out;

  char* ws = (char*)d_ws;
  signed char*    x8  = (signed char*)ws;                                       // 32 MiB
  signed char*    w8  = (signed char*)(ws + (size_t)M_ * K_);                   // 16 MiB
  unsigned short* xrb = (unsigned short*)(ws + (size_t)M_ * K_ + (size_t)N_ * K_);
  unsigned short* wob = xrb + (size_t)M_ * R_;

  (void)hipFuncSetAttribute((const void*)gemm_w4a4,
                            hipFuncAttributeMaxDynamicSharedMemorySize,
                            NBUF * TILE_SZ);

  repack_int4<<<2048, 256, 0, stream>>>(x_quant, (unsigned*)x8, M_ * KP_ / 4);
  repack_int4<<<2048, 256, 0, stream>>>(weight,  (unsigned*)w8, N_ * KP_ / 4);
  f2bf4<<<256, 256, 0, stream>>>(x_r, xrb, M_ * R_ / 4);
  f2bf4<<<128, 256, 0, stream>>>(w_outlier, wob, N_ * R_ / 4);

  gemm_w4a4<<<GRID, 512, NBUF * TILE_SZ, stream>>>(
      x8, w8, xrb, wob, x_scale, w_scales, bias, out);
}

// Round 3
// 170.064 us; speedup vs baseline: 1.0763x; 1.0763x over previous
//
#include <hip/hip_runtime.h>

// QuantLinearW4A4Tl: M=8192, K=4096, N=4096, R=32
#define M_ 8192
#define K_ 4096
#define N_ 4096
#define R_ 32
#define KP_ (K_ / 2)          // 2048 packed int32 per row

// GEMM: 256x256 tile, BK=64 i8, 8 waves (2Mx4N), 4-deep counted-vmcnt pipeline
#define BM 256
#define BN 256
#define BK 64
#define NT (K_ / BK)          // 64 K-tiles
#define ATILE 16384           // one operand tile: 16 frags x 1 KiB (frag-major)
#define TILE_SZ 32768         // A + B
#define GRID ((M_ / BM) * (N_ / BN))   // 32 x 16 = 512

typedef __attribute__((ext_vector_type(4))) int    i32x4;
typedef __attribute__((ext_vector_type(4))) float  f32x4;
typedef __attribute__((ext_vector_type(8))) __bf16 bf16x8;

__device__ __forceinline__ void gload16(const void* g, void* l) {
  __builtin_amdgcn_global_load_lds(
      (const __attribute__((address_space(1))) unsigned int*)g,
      (__attribute__((address_space(3))) unsigned int*)l, 16, 0, 0);
}

// int32 (2 nibbles, 0..255) -> 2 sign-extended int8 in a packed u16
__device__ __forceinline__ unsigned nib2(int b) {
  unsigned lo = (unsigned)(((b & 15) ^ 8) - 8) & 0xFFu;
  unsigned hi = (unsigned)((((b >> 4) & 15) ^ 8) - 8) & 0xFFu;
  return lo | (hi << 8);
}

// ---- tiled repack: emit the exact LDS image (frag-major) ----
// out granule (tile rt,kt; frag u; lane l) = 16 int8: row rt*256+u*16+(l&15),
// k = kt*64+(l>>4)*16 .. +15.  Staging in the GEMM becomes an identity copy;
// every gload16 then reads 64x16B CONTIGUOUS (fixes R2's 2x over-fetch).
__global__ void repack_tiled(const int* __restrict__ in, uint4* __restrict__ out) {
  const int tile = blockIdx.x;          // rt*64 + kt
  const int rt = tile >> 6, kt = tile & 63;
  const int t = threadIdx.x;            // 256 threads, 4 granules each
  #pragma unroll
  for (int i = 0; i < 4; ++i) {
    int g = t + i * 256;                // 0..1023
    int u = g >> 6, l = g & 63;
    int row = rt * 256 + u * 16 + (l & 15);
    int w0  = kt * 32 + (l >> 4) * 8;   // int32-word offset within row
    const int4* p = (const int4*)(in + (size_t)row * KP_ + w0);
    int4 a = p[0], b = p[1];
    uint4 o;
    o.x = nib2(a.x) | (nib2(a.y) << 16);
    o.y = nib2(a.z) | (nib2(a.w) << 16);
    o.z = nib2(b.x) | (nib2(b.y) << 16);
    o.w = nib2(b.z) | (nib2(b.w) << 16);
    out[(size_t)tile * 1024 + g] = o;
  }
}

// ---- f32 -> bf16 (RNE) ----
__device__ __forceinline__ unsigned short f2b(float x) {
  unsigned u = __float_as_uint(x);
  return (unsigned short)((u + 0x7FFFu + ((u >> 16) & 1u)) >> 16);
}

__global__ void f2bf4(const float* __restrict__ in, unsigned short* __restrict__ out, int n4) {
  int stride = gridDim.x * blockDim.x;
  for (int i = blockIdx.x * blockDim.x + threadIdx.x; i < n4; i += stride) {
    float4 f = ((const float4*)in)[i];
    ushort4 o;
    o.x = f2b(f.x); o.y = f2b(f.y); o.z = f2b(f.z); o.w = f2b(f.w);
    ((ushort4*)out)[i] = o;
  }
}

// ---- main GEMM ----
__global__ __launch_bounds__(512, 2) void gemm_w4a4(
    const char* __restrict__ x8t, const char* __restrict__ w8t,
    const unsigned short* __restrict__ xrb, const unsigned short* __restrict__ wob,
    const float* __restrict__ xscale, const float* __restrict__ wscale,
    const float* __restrict__ bias, float* __restrict__ out)
{
  extern __shared__ __align__(16) char lds[];   // 4 x 32 KiB

  const int t    = threadIdx.x;
  const int w    = t >> 6;          // wave 0..7
  const int l    = t & 63;
  const int lrow = l & 15;
  const int lgrp = l >> 4;
  const int wr   = w >> 2;          // 0..1 -> 128 output rows
  const int wc   = w & 3;           // 0..3 -> 64 output cols

  const int swz = (blockIdx.x & 7) * (GRID / 8) + (blockIdx.x >> 3);
  const int mt  = swz & 31, nt = swz >> 5;
  const int m0  = mt * BM, n0 = nt * BN;

  const char* aT = x8t + (size_t)mt * NT * ATILE;   // + kt*ATILE
  const char* bT = w8t + (size_t)nt * NT * ATILE;

  // wave w stages frag w (first load) and frag w+8 (second) of A and B;
  // source is the identity image, so src offset == LDS offset.
#define STAGE_A(tile)                                                         \
  { const char* s = aT + (size_t)(tile) * ATILE + w * 1024 + (l) * 16;        \
    char* d = lds + ((tile) & 3) * TILE_SZ + w * 1024;                        \
    gload16(s, d); gload16(s + 8192, d + 8192); }
#define STAGE_B(tile)                                                         \
  { const char* s = bT + (size_t)(tile) * ATILE + w * 1024 + (l) * 16;        \
    char* d = lds + ((tile) & 3) * TILE_SZ + ATILE + w * 1024;                \
    gload16(s, d); gload16(s + 8192, d + 8192); }
#define FENCE asm volatile("" ::: "memory")

  i32x4 acc[8][4] = {};

  // prologue: stage tiles 0..2 (12 loads/wave), wait tile 0 (8 younger remain)
  STAGE_A(0) STAGE_B(0)
  STAGE_A(1) STAGE_B(1)
  STAGE_A(2) STAGE_B(2)
  asm volatile("s_waitcnt vmcnt(8)" ::: "memory");
  __builtin_amdgcn_s_barrier();
  FENCE;

  for (int kt = 0; kt < NT; ++kt) {
    const char* Ab = lds + (kt & 3) * TILE_SZ;
    const char* Bb = Ab + ATILE;

    // ---- phase 1: ds_read B frags + A m 0..3; stage A(kt+3); MFMA x16 ----
    i32x4 bf[4], af0[4];
    #pragma unroll
    for (int n = 0; n < 4; ++n)
      bf[n] = *(const i32x4*)(Bb + (wc * 4 + n) * 1024 + l * 16);
    #pragma unroll
    for (int m = 0; m < 4; ++m)
      af0[m] = *(const i32x4*)(Ab + (wr * 8 + m) * 1024 + l * 16);
    if (kt < NT - 3) STAGE_A(kt + 3)
    FENCE;
    __builtin_amdgcn_s_barrier();
    FENCE;
    __builtin_amdgcn_s_setprio(1);
    #pragma unroll
    for (int m = 0; m < 4; ++m)
      #pragma unroll
      for (int n = 0; n < 4; ++n)
        acc[m][n] = __builtin_amdgcn_mfma_i32_16x16x64_i8(af0[m], bf[n], acc[m][n], 0, 0, 0);
    __builtin_amdgcn_s_setprio(0);
    FENCE;
    __builtin_amdgcn_s_barrier();
    FENCE;

    // ---- phase 2: ds_read A m 4..7; stage B(kt+3); counted vmcnt; MFMA x16 ----
    i32x4 af1[4];
    #pragma unroll
    for (int m = 0; m < 4; ++m)
      af1[m] = *(const i32x4*)(Ab + (wr * 8 + 4 + m) * 1024 + l * 16);
    if (kt < NT - 3) {
      STAGE_B(kt + 3)
      // in flight: kt+1 (4), kt+2 (4), kt+3 (4); need kt+1 landed -> vmcnt(8)
      asm volatile("s_waitcnt vmcnt(8)" ::: "memory");
    } else if (kt == NT - 3) {
      asm volatile("s_waitcnt vmcnt(4)" ::: "memory");
    } else if (kt == NT - 2) {
      asm volatile("s_waitcnt vmcnt(0)" ::: "memory");
    }
    FENCE;
    __builtin_amdgcn_s_barrier();
    FENCE;
    __builtin_amdgcn_s_setprio(1);
    #pragma unroll
    for (int m = 0; m < 4; ++m)
      #pragma unroll
      for (int n = 0; n < 4; ++n)
        acc[4 + m][n] = __builtin_amdgcn_mfma_i32_16x16x64_i8(af1[m], bf[n], acc[4 + m][n], 0, 0, 0);
    __builtin_amdgcn_s_setprio(0);
    FENCE;
    __builtin_amdgcn_s_barrier();
    FENCE;
  }

  // ---- epilogue: dequant + bias + rank-32 outlier via bf16 MFMA ----
  f32x4 sxv[8];
  #pragma unroll
  for (int m = 0; m < 8; ++m)
    sxv[m] = *(const f32x4*)(xscale + m0 + wr * 128 + m * 16 + lgrp * 4);
  float swv[4], bv[4];
  #pragma unroll
  for (int n = 0; n < 4; ++n) {
    int cg = n0 + wc * 64 + n * 16 + lrow;
    swv[n] = wscale[cg];
    bv[n]  = bias[cg];
  }
  bf16x8 ar[8], br[4];
  #pragma unroll
  for (int m = 0; m < 8; ++m)
    ar[m] = *(const bf16x8*)(xrb + (size_t)(m0 + wr * 128 + m * 16 + lrow) * R_ + lgrp * 8);
  #pragma unroll
  for (int n = 0; n < 4; ++n)
    br[n] = *(const bf16x8*)(wob + (size_t)(n0 + wc * 64 + n * 16 + lrow) * R_ + lgrp * 8);

  #pragma unroll
  for (int m = 0; m < 8; ++m) {
    #pragma unroll
    for (int n = 0; n < 4; ++n) {
      f32x4 z = {0.0f, 0.0f, 0.0f, 0.0f};
      f32x4 c = __builtin_amdgcn_mfma_f32_16x16x32_bf16(ar[m], br[n], z, 0, 0, 0);
      #pragma unroll
      for (int j = 0; j < 4; ++j) {
        int rg = m0 + wr * 128 + m * 16 + lgrp * 4 + j;   // C/D: row=(l>>4)*4+j
        int cg = n0 + wc * 64 + n * 16 + lrow;            //      col=l&15
        out[(size_t)rg * N_ + cg] =
            (float)acc[m][n][j] * sxv[m][j] * swv[n] + c[j] + bv[n];
      }
    }
  }
}

extern "C" void kernel_launch(void* const* d_in, const int* in_sizes, int n_in,
                              void* d_out, int out_size, void* d_ws, size_t ws_size,
                              hipStream_t stream) {
  const int*   x_quant   = (const int*)d_in[0];
  const float* x_scale   = (const float*)d_in[1];
  const int*   weight    = (const int*)d_in[2];
  const float* w_scales  = (const float*)d_in[3];
  const float* bias      = (const float*)d_in[4];
  const float* x_r       = (const float*)d_in[5];
  const float* w_outlier = (const float*)d_in[6];
  float* out = (float*)d_out;

  char* ws = (char*)d_ws;
  char*           x8t = ws;                                       // 32 MiB, tiled
  char*           w8t = ws + (size_t)M_ * K_;                     // 16 MiB, tiled
  unsigned short* xrb = (unsigned short*)(ws + (size_t)M_ * K_ + (size_t)N_ * K_);
  unsigned short* wob = xrb + (size_t)M_ * R_;

  (void)hipFuncSetAttribute((const void*)gemm_w4a4,
                            hipFuncAttributeMaxDynamicSharedMemorySize,
                            4 * TILE_SZ);

  repack_tiled<<<(M_ / BM) * NT, 256, 0, stream>>>(x_quant, (uint4*)x8t);
  repack_tiled<<<(N_ / BN) * NT, 256, 0, stream>>>(weight,  (uint4*)w8t);
  f2bf4<<<256, 256, 0, stream>>>(x_r, xrb, M_ * R_ / 4);
  f2bf4<<<128, 256, 0, stream>>>(w_outlier, wob, N_ * R_ / 4);

  gemm_w4a4<<<GRID, 512, 4 * TILE_SZ, stream>>>(
      x8t, w8t, xrb, wob, x_scale, w_scales, bias, out);
}